// Round 10
// baseline (240.991 us; speedup 1.0000x reference)
//
#include <hip/hip_runtime.h>

typedef __bf16 bf16;
typedef __bf16 bf16x8 __attribute__((ext_vector_type(8)));
typedef float f32x4 __attribute__((ext_vector_type(4)));

#define NIMG 16
#define CCH 256
#define HH 56
#define HP 58
#define NBLK (NIMG * 14)         // 224 conv blocks (4 rows each)
#define NPART 896                // 224 blocks * 4 rows
#define NPOSV (NIMG * HH * HH)   // 50176 valid positions
#define WELEMS 589824            // 256*256*3*3
#define NRED 32                  // reducer blocks

typedef const __attribute__((address_space(1))) void* gas1_t;
typedef __attribute__((address_space(3))) void* las3_t;

__device__ __forceinline__ void gload16(const void* g, void* l) {
  __builtin_amdgcn_global_load_lds((gas1_t)g, (las3_t)l, 16, 0, 0);
}

// ---------------- counters ----------------
__global__ void zero_cnt(unsigned* c) { c[threadIdx.x] = 0u; }

// ---------------- weight quantization ----------------

__global__ __launch_bounds__(256) void w_partial(const float* __restrict__ w1,
                                                 const float* __restrict__ w2,
                                                 double* __restrict__ psum,
                                                 float* __restrict__ pmn,
                                                 float* __restrict__ pmx) {
  int b = blockIdx.x;            // 256 blocks: 128 per weight
  int lb = b & 127;
  const float* w = (b >> 7) ? w2 : w1;
  int t = threadIdx.x;
  double s = 0.0;
  float mn = 3.4028235e38f, mx = -3.4028235e38f;
  for (int i = lb * 4608 + t; i < (lb + 1) * 4608; i += 256) {
    float v = w[i];
    s += (double)v;
    mn = fminf(mn, v);
    mx = fmaxf(mx, v);
  }
  __shared__ double sd[256];
  __shared__ float smn[256], smx[256];
  sd[t] = s; smn[t] = mn; smx[t] = mx;
  __syncthreads();
  for (int st = 128; st > 0; st >>= 1) {
    if (t < st) {
      sd[t] += sd[t + st];
      smn[t] = fminf(smn[t], smn[t + st]);
      smx[t] = fmaxf(smx[t], smx[t + st]);
    }
    __syncthreads();
  }
  if (t == 0) { psum[b] = sd[0]; pmn[b] = smn[0]; pmx[b] = smx[0]; }
}

__global__ void w_finalize(const double* __restrict__ psum,
                           const float* __restrict__ pmn,
                           const float* __restrict__ pmx,
                           float* __restrict__ wq) {
  int t = threadIdx.x;
  if (t < 2) {
    double s = 0.0;
    float mn = 3.4028235e38f, mx = -3.4028235e38f;
    for (int b = t * 128; b < (t + 1) * 128; b++) {
      s += psum[b];
      mn = fminf(mn, pmn[b]);
      mx = fmaxf(mx, pmx[b]);
    }
    float mean = (float)(s / (double)WELEMS);
    float tmn = mn - mean, tmx = mx - mean;
    float d = (tmx - tmn) / 3.0f;
    wq[t * 4 + 0] = mean;
    wq[t * 4 + 1] = tmn + d;   // lo
    wq[t * 4 + 2] = tmx - d;   // hi
  }
}

// Fragment-major B table: element e = fragidx*512 + l*8 + ki
// fragidx = ((s*4+cc)*2+kk)*16 + ob ; lane l: o = ob*16+(l&15), c = cc*64+kk*32+(l>>4)*8+ki
__global__ __launch_bounds__(256) void w_quant(const float* __restrict__ w1,
                                               const float* __restrict__ w2,
                                               const float* __restrict__ wq,
                                               bf16* __restrict__ btf1,
                                               bf16* __restrict__ btf2) {
  int bid = blockIdx.x;          // 4608 blocks
  int widx = bid / 2304;
  const float* w = widx ? w2 : w1;
  bf16* bt = widx ? btf2 : btf1;
  float mean = wq[widx * 4], lo = wq[widx * 4 + 1], hi = wq[widx * 4 + 2];
  int e = (bid % 2304) * 256 + threadIdx.x;
  int ki = e & 7;
  int l = (e >> 3) & 63;
  int frag = e >> 9;
  int ob = frag & 15;
  int rest = frag >> 4;
  int kk = rest & 1;
  int scc = rest >> 1;
  int cc = scc & 3;
  int s = scc >> 2;
  int o = ob * 16 + (l & 15);
  int c = cc * 64 + kk * 32 + (l >> 4) * 8 + ki;
  float tv = w[(size_t)o * 2304 + c * 9 + s] - mean;
  float q = tv < lo ? -1.f : (tv > hi ? 1.f : 0.f);
  if (s == 4) q *= 2.f;          // fold the "extra" center einsum in
  bt[e] = (bf16)q;
}

// ---------------- NCHW fp32 -> padded NHWC bf16 (vectorized) ----------------
__global__ __launch_bounds__(256) void pad_convert(const float* __restrict__ x,
                                                   bf16* __restrict__ xpad) {
  int bid = blockIdx.x;
  int hp = bid % HP;
  int n = bid / HP;
  int t = threadIdx.x;
  bf16* orow = xpad + (size_t)(n * HP + hp) * HP * CCH;
  bf16x8 z;
#pragma unroll
  for (int q = 0; q < 8; ++q) z[q] = (bf16)0.f;
  if (hp == 0 || hp == HP - 1) {
    for (int j = t; j < HP * 32; j += 256)
      *(bf16x8*)(orow + (size_t)(j >> 5) * CCH + (j & 31) * 8) = z;
    return;
  }
  __shared__ float tile[CCH * 57];
  const float* xb = x + (size_t)n * CCH * (HH * HH) + (size_t)(hp - 1) * HH;
  for (int j = t; j < CCH * 14; j += 256) {
    int c = j / 14, wq = j % 14;
    float4 v = *(const float4*)(xb + (size_t)c * (HH * HH) + wq * 4);
    float* tp = &tile[c * 57 + wq * 4];
    tp[0] = v.x; tp[1] = v.y; tp[2] = v.z; tp[3] = v.w;
  }
  __syncthreads();
  const int cg = t & 31;
  for (int j = t; j < HP * 32; j += 256) {
    int wp = j >> 5;                 // (j & 31) == cg
    bf16x8 ov = z;
    if (wp >= 1 && wp <= HH) {
#pragma unroll
      for (int q = 0; q < 8; ++q) ov[q] = (bf16)tile[(cg * 8 + q) * 57 + (wp - 1)];
    }
    *(bf16x8*)(orow + (size_t)wp * CCH + cg * 8) = ov;
  }
}

// ---------------- cooperative conv: GEMM + in-kernel BN reduce + fused epilogue ----------
// MODE 1: epilogue = bn1+relu -> bf16 written IN-PLACE into xpad (valid: post-barrier)
// MODE 2: epilogue = bn2 + residual(v1pad) + relu -> NCHW fp32 (outf)
template <int MODE>
__global__ __launch_bounds__(512, 2) void conv_coop(const bf16* __restrict__ xpad,
                                                    const bf16* __restrict__ btf,
                                                    float* __restrict__ part,
                                                    float* __restrict__ part2,
                                                    const float* __restrict__ gamma,
                                                    const float* __restrict__ beta,
                                                    const bf16* __restrict__ v1pad,
                                                    bf16* __restrict__ outb,
                                                    float* __restrict__ outf,
                                                    unsigned* __restrict__ cnt_a,
                                                    unsigned* __restrict__ cnt_b) {
  __shared__ __align__(16) char smem[116736];   // conv: 2x48KB A bufs; MODE2 epi: 8 tiles
  const int t = threadIdx.x;
  const int lane = t & 63, wv = t >> 6;
  const int wm = wv >> 2, wn = wv & 3;          // wave: rows 2wm..2wm+1, o-chunk wn
  const int g = lane >> 4, li = lane & 15;
  const int rawbid = blockIdx.x;
  const int bid = (rawbid & 7) * (NBLK / 8) + (rawbid >> 3);  // XCD-contiguous swizzle
  const int n = bid / 14, h0 = (bid % 14) * 4;

  f32x4 acc[8][4];
#pragma unroll
  for (int i = 0; i < 8; i++)
#pragma unroll
    for (int j = 0; j < 4; j++) acc[i][j] = f32x4{0.f, 0.f, 0.f, 0.f};

  auto stageA = [&](int cc, int b) {
#pragma unroll
    for (int i = 0; i < 6; ++i) {
      int idx = wv + i * 8;              // 0..47
      int rr = idx >> 3, po = idx & 7;
      int pp = po * 8 + (lane >> 3);
      int gs = (lane & 7) ^ (lane >> 3); // inverse swizzle on source
      const bf16* src = xpad + ((size_t)(n * HP + h0 + rr) * HP + pp) * CCH + cc * 64 + gs * 8;
      gload16(src, smem + b * 49152 + rr * 8192 + po * 1024 + lane * 16);
    }
  };

  auto loadB = [&](bf16x8 (&dst)[4], int s, int cc, int kk) {
#pragma unroll
    for (int f = 0; f < 4; ++f) {
      size_t fragidx = (size_t)(((s * 4 + cc) * 2 + kk) * 16 + wn * 4 + f);
      dst[f] = *(const bf16x8*)(btf + fragidx * 512 + lane * 8);
    }
  };

  auto compute_half = [&](const char* Ab, int half, int dh, int dw, int kk,
                          const bf16x8 (&bx)[4]) {
    bf16x8 a[4];
    int rr = 2 * wm + half + dh;
#pragma unroll
    for (int pc = 0; pc < 4; ++pc) {
      int p = pc * 16 + li + dw;
      int sl = (kk * 4 + g) ^ (p & 7);
      a[pc] = *(const bf16x8*)(Ab + rr * 8192 + p * 128 + sl * 16);
    }
#pragma unroll
    for (int pc = 0; pc < 4; ++pc)
#pragma unroll
      for (int fn = 0; fn < 4; ++fn)
        acc[half * 4 + pc][fn] =
          __builtin_amdgcn_mfma_f32_16x16x32_bf16(a[pc], bx[fn], acc[half * 4 + pc][fn], 0, 0, 0);
  };

  stageA(0, 0);
  bf16x8 bS[2][4];
  bf16x8 bB[4];
  loadB(bS[0], 0, 0, 0);
  __syncthreads();

#pragma unroll
  for (int cc = 0; cc < 4; ++cc) {
    const char* Ab = smem + (cc & 1) * 49152;
    if (cc < 3) stageA(cc + 1, (cc + 1) & 1);
#pragma unroll
    for (int s = 0; s < 9; ++s) {
      const int dh = s / 3, dw = s % 3;
      const int cur = (cc * 9 + s) & 1, nxt = cur ^ 1;
      if (s < 8) loadB(bS[nxt], s + 1, cc, 0);
      else if (cc < 3) loadB(bS[nxt], 0, cc + 1, 0);
      loadB(bB, s, cc, 1);
      __builtin_amdgcn_sched_barrier(0);
      __builtin_amdgcn_s_setprio(1);
      compute_half(Ab, 0, dh, dw, 0, bS[cur]);
      compute_half(Ab, 1, dh, dw, 0, bS[cur]);
      compute_half(Ab, 0, dh, dw, 1, bB);
      compute_half(Ab, 1, dh, dw, 1, bB);
      __builtin_amdgcn_s_setprio(0);
    }
    __syncthreads();
  }

  // ---- per-block BN stats partials ----
  {
    float so[2][4] = {{0.f,0.f,0.f,0.f},{0.f,0.f,0.f,0.f}};
    float qo[2][4] = {{0.f,0.f,0.f,0.f},{0.f,0.f,0.f,0.f}};
#pragma unroll
    for (int fm = 0; fm < 8; ++fm) {
      const int rl = fm >> 2, pc = fm & 3;
#pragma unroll
      for (int r = 0; r < 4; ++r) {
        int w = pc * 16 + g * 4 + r;
        if (w < HH) {
#pragma unroll
          for (int fn = 0; fn < 4; ++fn) {
            float v = acc[fm][fn][r];
            so[rl][fn] += v;
            qo[rl][fn] += v * v;
          }
        }
      }
    }
#pragma unroll
    for (int rl = 0; rl < 2; ++rl)
#pragma unroll
      for (int fn = 0; fn < 4; ++fn) {
        so[rl][fn] += __shfl_xor(so[rl][fn], 16);
        so[rl][fn] += __shfl_xor(so[rl][fn], 32);
        qo[rl][fn] += __shfl_xor(qo[rl][fn], 16);
        qo[rl][fn] += __shfl_xor(qo[rl][fn], 32);
      }
    if (g == 0) {
#pragma unroll
      for (int rl = 0; rl < 2; ++rl)
#pragma unroll
        for (int fn = 0; fn < 4; ++fn) {
          int o = wn * 64 + fn * 16 + lane;
          size_t prow = (size_t)(bid * 4 + 2 * wm + rl);
          part[(prow * CCH + o) * 2 + 0] = so[rl][fn];
          part[(prow * CCH + o) * 2 + 1] = qo[rl][fn];
        }
    }
  }

  // ---- grid barrier A: all partials visible ----
  __syncthreads();
  if (t == 0) {
    __threadfence();
    atomicAdd(cnt_a, 1u);
  }
  // ---- reducer blocks (rawbid 0..31): 28 rows each -> part2 ----
  if (rawbid < NRED) {
    if (t == 0) {
      while (atomicAdd(cnt_a, 0u) < (unsigned)NBLK) __builtin_amdgcn_s_sleep(2);
      __threadfence();
    }
    __syncthreads();
    if (t < 256) {
      float s = 0.f, q = 0.f;
      for (int r = rawbid * 28; r < (rawbid + 1) * 28; r++) {
        s += part[((size_t)r * CCH + t) * 2 + 0];
        q += part[((size_t)r * CCH + t) * 2 + 1];
      }
      part2[((size_t)rawbid * CCH + t) * 2 + 0] = s;
      part2[((size_t)rawbid * CCH + t) * 2 + 1] = q;
    }
    __syncthreads();
    if (t == 0) {
      __threadfence();
      atomicAdd(cnt_b, 1u);
    }
  }
  // ---- grid barrier B: part2 complete ----
  if (t == 0) {
    while (atomicAdd(cnt_b, 0u) < (unsigned)NRED) __builtin_amdgcn_s_sleep(2);
    __threadfence();
  }
  __syncthreads();

  // ---- per-lane affine for this wave's 4 channels ----
  float sc[4], bi[4];
  const float inv = 1.f / (float)NPOSV;
#pragma unroll
  for (int fn = 0; fn < 4; ++fn) {
    int o = wn * 64 + fn * 16 + li;
    float s = 0.f, q = 0.f;
    for (int b = 0; b < NRED; ++b) {
      s += part2[((size_t)b * CCH + o) * 2 + 0];
      q += part2[((size_t)b * CCH + o) * 2 + 1];
    }
    float mean = s * inv;
    float var = q * inv - mean * mean;
    float scale = gamma[o] / sqrtf(var + 1e-5f);
    sc[fn] = scale;
    bi[fn] = beta[o] - mean * scale;
  }

  if (MODE == 1) {
    // bn1 + relu -> bf16, in-place into xpad interior (borders remain zero)
#pragma unroll
    for (int fm = 0; fm < 8; ++fm) {
      const int rl = fm >> 2, pc = fm & 3;
      const int h = h0 + 2 * wm + rl;
      bf16* obase = outb + ((size_t)(n * HP + h + 1) * HP + 1) * CCH;
#pragma unroll
      for (int r = 0; r < 4; ++r) {
        int w = pc * 16 + g * 4 + r;
        if (w < HH) {
#pragma unroll
          for (int fn = 0; fn < 4; ++fn) {
            float v = acc[fm][fn][r] * sc[fn] + bi[fn];
            v = v > 0.f ? v : 0.f;
            obase[(size_t)w * CCH + wn * 64 + fn * 16 + li] = (bf16)v;
          }
        }
      }
    }
  } else {
    // MODE 2: bn2 + residual + relu, per-wave LDS tile, transpose to NCHW
    float* fsm = (float*)smem;
    const int TS = 3648;   // floats per tile (56 rows x 65 stride)
    for (int rl = 0; rl < 2; ++rl) {
      __syncthreads();
      const int row = h0 + 2 * wm + rl;
#pragma unroll
      for (int pc = 0; pc < 4; ++pc) {
        const int fm = rl * 4 + pc;
#pragma unroll
        for (int r = 0; r < 4; ++r) {
          int w = pc * 16 + g * 4 + r;
          if (w < HH) {
#pragma unroll
            for (int fn = 0; fn < 4; ++fn) {
              int o_loc = fn * 16 + li;
              fsm[wv * TS + w * 65 + o_loc] = acc[fm][fn][r] * sc[fn] + bi[fn];
            }
          }
        }
      }
      const bf16* v1row = v1pad + ((size_t)(n * HP + row + 1) * HP + 1) * CCH + wn * 64;
      for (int i = lane; i < HH * 8; i += 64) {
        int w = i >> 3, og = i & 7;
        bf16x8 v1v = *(const bf16x8*)(v1row + (size_t)w * CCH + og * 8);
        float* tp = &fsm[wv * TS + w * 65 + og * 8];
#pragma unroll
        for (int q = 0; q < 8; ++q) {
          float v = tp[q] + (float)v1v[q];
          tp[q] = v > 0.f ? v : 0.f;
        }
      }
      __syncthreads();
#pragma unroll
      for (int tl = 0; tl < 8; ++tl) {
        int wmt = tl >> 2, wnt = tl & 3;
        int orow = h0 + 2 * wmt + rl;
        for (int j = t; j < 4096; j += 512) {
          int oo = j >> 6, w = j & 63;
          if (w < HH)
            outf[(((size_t)n * CCH + wnt * 64 + oo) * HH + orow) * HH + w] = fsm[tl * TS + w * 65 + oo];
        }
      }
    }
  }
}

// ---------------- launch ----------------

extern "C" void kernel_launch(void* const* d_in, const int* in_sizes, int n_in,
                              void* d_out, int out_size, void* d_ws, size_t ws_size,
                              hipStream_t stream) {
  const float* x  = (const float*)d_in[0];
  const float* w1 = (const float*)d_in[1];
  const float* w2 = (const float*)d_in[2];
  const float* g1 = (const float*)d_in[3];
  const float* b1 = (const float*)d_in[4];
  const float* g2 = (const float*)d_in[5];
  const float* b2 = (const float*)d_in[6];
  float* out = (float*)d_out;
  char* ws = (char*)d_ws;

  constexpr size_t O_BT1  = 0;                                   // 1,179,648
  constexpr size_t O_BT2  = O_BT1 + 1179648;
  constexpr size_t O_XPAD = O_BT2 + 1179648;                     // 27,557,888
  constexpr size_t O_PART = O_XPAD + (size_t)NIMG * HP * HP * CCH * 2 + 65536;
  constexpr size_t O_PSUM = O_PART + (size_t)NPART * CCH * 2 * 4; // part: 1,835,008
  constexpr size_t O_PMN  = O_PSUM + 2048;
  constexpr size_t O_PMX  = O_PMN + 1024;
  constexpr size_t O_WQ   = O_PMX + 1024;
  constexpr size_t O_PART2 = O_WQ + 256;                         // 65,536
  constexpr size_t O_CNT  = O_PART2 + 65536;                     // 4 uints

  bf16* bt1 = (bf16*)(ws + O_BT1);
  bf16* bt2 = (bf16*)(ws + O_BT2);
  bf16* xpad = (bf16*)(ws + O_XPAD);     // conv1 rewrites it in-place as out1pad
  float* part = (float*)(ws + O_PART);
  double* psum = (double*)(ws + O_PSUM);
  float* pmn = (float*)(ws + O_PMN);
  float* pmx = (float*)(ws + O_PMX);
  float* wq = (float*)(ws + O_WQ);
  float* part2 = (float*)(ws + O_PART2);
  unsigned* cnt = (unsigned*)(ws + O_CNT);

  zero_cnt<<<1, 4, 0, stream>>>(cnt);
  w_partial<<<256, 256, 0, stream>>>(w1, w2, psum, pmn, pmx);
  w_finalize<<<1, 64, 0, stream>>>(psum, pmn, pmx, wq);
  w_quant<<<4608, 256, 0, stream>>>(w1, w2, wq, bt1, bt2);
  pad_convert<<<NIMG * HP, 256, 0, stream>>>(x, xpad);
  // conv1: GEMM + grid-barrier BN1 + bn1/relu epilogue in-place (xpad -> out1pad)
  conv_coop<1><<<NBLK, 512, 0, stream>>>(xpad, bt1, part, part2, g1, b1,
                                         nullptr, xpad, nullptr, cnt + 0, cnt + 1);
  // conv2: GEMM + grid-barrier BN2 + bn2+residual+relu+transpose epilogue -> out
  conv_coop<2><<<NBLK, 512, 0, stream>>>(xpad, bt2, part, part2, g2, b2,
                                         xpad, nullptr, out, cnt + 2, cnt + 3);
}

// Round 11
// 219.733 us; speedup vs baseline: 1.0967x; 1.0967x over previous
//
#include <hip/hip_runtime.h>

typedef __bf16 bf16;
typedef __bf16 bf16x8 __attribute__((ext_vector_type(8)));
typedef float f32x4 __attribute__((ext_vector_type(4)));

#define NIMG 16
#define CCH 256
#define HH 56
#define HP 58
#define NBLK (NIMG * 14)         // 224 conv blocks (4 rows each)
#define NPART 896                // 224 blocks * 4 rows
#define NPOSV (NIMG * HH * HH)   // 50176 valid positions
#define WELEMS 589824            // 256*256*3*3

typedef const __attribute__((address_space(1))) void* gas1_t;
typedef __attribute__((address_space(3))) void* las3_t;

__device__ __forceinline__ void gload16(const void* g, void* l) {
  __builtin_amdgcn_global_load_lds((gas1_t)g, (las3_t)l, 16, 0, 0);
}

// ---------------- weight quantization ----------------

__global__ __launch_bounds__(256) void w_partial(const float* __restrict__ w1,
                                                 const float* __restrict__ w2,
                                                 double* __restrict__ psum,
                                                 float* __restrict__ pmn,
                                                 float* __restrict__ pmx) {
  int b = blockIdx.x;            // 256 blocks: 128 per weight
  int lb = b & 127;
  const float* w = (b >> 7) ? w2 : w1;
  int t = threadIdx.x;
  double s = 0.0;
  float mn = 3.4028235e38f, mx = -3.4028235e38f;
  for (int i = lb * 4608 + t; i < (lb + 1) * 4608; i += 256) {
    float v = w[i];
    s += (double)v;
    mn = fminf(mn, v);
    mx = fmaxf(mx, v);
  }
  __shared__ double sd[256];
  __shared__ float smn[256], smx[256];
  sd[t] = s; smn[t] = mn; smx[t] = mx;
  __syncthreads();
  for (int st = 128; st > 0; st >>= 1) {
    if (t < st) {
      sd[t] += sd[t + st];
      smn[t] = fminf(smn[t], smn[t + st]);
      smx[t] = fmaxf(smx[t], smx[t + st]);
    }
    __syncthreads();
  }
  if (t == 0) { psum[b] = sd[0]; pmn[b] = smn[0]; pmx[b] = smx[0]; }
}

__global__ void w_finalize(const double* __restrict__ psum,
                           const float* __restrict__ pmn,
                           const float* __restrict__ pmx,
                           float* __restrict__ wq) {
  int t = threadIdx.x;
  if (t < 2) {
    double s = 0.0;
    float mn = 3.4028235e38f, mx = -3.4028235e38f;
    for (int b = t * 128; b < (t + 1) * 128; b++) {
      s += psum[b];
      mn = fminf(mn, pmn[b]);
      mx = fmaxf(mx, pmx[b]);
    }
    float mean = (float)(s / (double)WELEMS);
    float tmn = mn - mean, tmx = mx - mean;
    float d = (tmx - tmn) / 3.0f;
    wq[t * 4 + 0] = mean;
    wq[t * 4 + 1] = tmn + d;   // lo
    wq[t * 4 + 2] = tmx - d;   // hi
  }
}

// Fragment-major B table: element e = fragidx*512 + l*8 + ki
// fragidx = ((s*4+cc)*2+kk)*16 + ob ; lane l: o = ob*16+(l&15), c = cc*64+kk*32+(l>>4)*8+ki
__global__ __launch_bounds__(256) void w_quant(const float* __restrict__ w1,
                                               const float* __restrict__ w2,
                                               const float* __restrict__ wq,
                                               bf16* __restrict__ btf1,
                                               bf16* __restrict__ btf2) {
  int bid = blockIdx.x;          // 4608 blocks
  int widx = bid / 2304;
  const float* w = widx ? w2 : w1;
  bf16* bt = widx ? btf2 : btf1;
  float mean = wq[widx * 4], lo = wq[widx * 4 + 1], hi = wq[widx * 4 + 2];
  int e = (bid % 2304) * 256 + threadIdx.x;
  int ki = e & 7;
  int l = (e >> 3) & 63;
  int frag = e >> 9;
  int ob = frag & 15;
  int rest = frag >> 4;
  int kk = rest & 1;
  int scc = rest >> 1;
  int cc = scc & 3;
  int s = scc >> 2;
  int o = ob * 16 + (l & 15);
  int c = cc * 64 + kk * 32 + (l >> 4) * 8 + ki;
  float tv = w[(size_t)o * 2304 + c * 9 + s] - mean;
  float q = tv < lo ? -1.f : (tv > hi ? 1.f : 0.f);
  if (s == 4) q *= 2.f;          // fold the "extra" center einsum in
  bt[e] = (bf16)q;
}

// ---------------- NCHW fp32 -> padded NHWC bf16 (vectorized) ----------------
__global__ __launch_bounds__(256) void pad_convert(const float* __restrict__ x,
                                                   bf16* __restrict__ xpad) {
  int bid = blockIdx.x;
  int hp = bid % HP;
  int n = bid / HP;
  int t = threadIdx.x;
  bf16* orow = xpad + (size_t)(n * HP + hp) * HP * CCH;
  bf16x8 z;
#pragma unroll
  for (int q = 0; q < 8; ++q) z[q] = (bf16)0.f;
  if (hp == 0 || hp == HP - 1) {
    for (int j = t; j < HP * 32; j += 256)
      *(bf16x8*)(orow + (size_t)(j >> 5) * CCH + (j & 31) * 8) = z;
    return;
  }
  __shared__ float tile[CCH * 57];
  const float* xb = x + (size_t)n * CCH * (HH * HH) + (size_t)(hp - 1) * HH;
  for (int j = t; j < CCH * 14; j += 256) {
    int c = j / 14, wq = j % 14;
    float4 v = *(const float4*)(xb + (size_t)c * (HH * HH) + wq * 4);
    float* tp = &tile[c * 57 + wq * 4];
    tp[0] = v.x; tp[1] = v.y; tp[2] = v.z; tp[3] = v.w;
  }
  __syncthreads();
  const int cg = t & 31;
  for (int j = t; j < HP * 32; j += 256) {
    int wp = j >> 5;                 // (j & 31) == cg
    bf16x8 ov = z;
    if (wp >= 1 && wp <= HH) {
#pragma unroll
      for (int q = 0; q < 8; ++q) ov[q] = (bf16)tile[(cg * 8 + q) * 57 + (wp - 1)];
    }
    *(bf16x8*)(orow + (size_t)wp * CCH + cg * 8) = ov;
  }
}

// ---------------- conv as implicit GEMM ----------------
// block 256Mx256N, 4 waves (1/SIMD), wave tile 128Mx128N: acc 8x8 f32x4 = 256 regs.
// Halves per-CU LDS A-read redundancy vs the 8-wave 128x64 layout (was LDS-bound at 45%).
// Epilogue: fused BN stats partials + raw NHWC bf16 write.
__global__ __launch_bounds__(256, 1) void conv_gemm(const bf16* __restrict__ xpad,
                                                    const bf16* __restrict__ btf,
                                                    float* __restrict__ part,
                                                    bf16* __restrict__ outb) {
  __shared__ __align__(16) char smem[98304];   // 2 x 48KB A double-buffer
  const int t = threadIdx.x;
  const int lane = t & 63, wv = t >> 6;        // 4 waves
  const int wm = wv >> 1, wn = wv & 1;         // wave: rows 2wm..2wm+1, o-half wn
  const int g = lane >> 4, li = lane & 15;
  const int rawbid = blockIdx.x;
  const int bid = (rawbid & 7) * (NBLK / 8) + (rawbid >> 3);  // XCD-contiguous swizzle
  const int n = bid / 14, h0 = (bid % 14) * 4;

  f32x4 acc[8][8];
#pragma unroll
  for (int i = 0; i < 8; i++)
#pragma unroll
    for (int j = 0; j < 8; j++) acc[i][j] = f32x4{0.f, 0.f, 0.f, 0.f};

  // ---- A staging: chunk cc (64 ch) -> buffer b; 6 rows x 64 pos, swizzled granules
  auto stageA = [&](int cc, int b) {
#pragma unroll
    for (int i = 0; i < 12; ++i) {
      int idx = wv + i * 4;              // 0..47
      int rr = idx >> 3, po = idx & 7;
      int pp = po * 8 + (lane >> 3);
      int gs = (lane & 7) ^ (lane >> 3); // inverse swizzle on source (pp&7 == lane>>3)
      const bf16* src = xpad + ((size_t)(n * HP + h0 + rr) * HP + pp) * CCH + cc * 64 + gs * 8;
      gload16(src, smem + b * 49152 + rr * 8192 + po * 1024 + lane * 16);
    }
  };

  // ---- B fragment loads: wave's 8 frags (o-half wn) for (s,cc,kk), coalesced from L2
  auto loadB = [&](bf16x8 (&dst)[8], int s, int cc, int kk) {
#pragma unroll
    for (int f = 0; f < 8; ++f) {
      size_t fragidx = (size_t)(((s * 4 + cc) * 2 + kk) * 16 + wn * 8 + f);
      dst[f] = *(const bf16x8*)(btf + fragidx * 512 + lane * 8);
    }
  };

  // ---- one k-half: 8 A-frags from LDS + 64 MFMA against bx[8]
  auto compute_kk = [&](const char* Ab, int dh, int dw, int kk, const bf16x8 (&bx)[8]) {
    bf16x8 a[8];
#pragma unroll
    for (int pc = 0; pc < 8; ++pc) {
      int rr = 2 * wm + (pc >> 2) + dh;
      int p = (pc & 3) * 16 + li + dw;
      int sl = (kk * 4 + g) ^ (p & 7);
      a[pc] = *(const bf16x8*)(Ab + rr * 8192 + p * 128 + sl * 16);
    }
#pragma unroll
    for (int pc = 0; pc < 8; ++pc)
#pragma unroll
      for (int fn = 0; fn < 8; ++fn)
        acc[pc][fn] =
          __builtin_amdgcn_mfma_f32_16x16x32_bf16(a[pc], bx[fn], acc[pc][fn], 0, 0, 0);
  };

  stageA(0, 0);
  bf16x8 bS[2][8];   // kk=0 ping-pong, prefetched one full tap-phase ahead
  bf16x8 bB[8];      // kk=1, loaded at phase start, covered by kk=0 compute
  loadB(bS[0], 0, 0, 0);
  __syncthreads();

#pragma unroll
  for (int cc = 0; cc < 4; ++cc) {
    const char* Ab = smem + (cc & 1) * 49152;
    if (cc < 3) stageA(cc + 1, (cc + 1) & 1);
#pragma unroll
    for (int s = 0; s < 9; ++s) {
      const int dh = s / 3, dw = s % 3;
      const int cur = (cc * 9 + s) & 1, nxt = cur ^ 1;
      if (s < 8) loadB(bS[nxt], s + 1, cc, 0);
      else if (cc < 3) loadB(bS[nxt], 0, cc + 1, 0);
      loadB(bB, s, cc, 1);
      __builtin_amdgcn_sched_barrier(0);   // keep load issues above the MFMA cluster
      __builtin_amdgcn_s_setprio(1);
      compute_kk(Ab, dh, dw, 0, bS[cur]);
      compute_kk(Ab, dh, dw, 1, bB);
      __builtin_amdgcn_s_setprio(0);
    }
    __syncthreads();
  }

  // ---- fused BN stats partials + raw bf16 NHWC write ----
  float so[2][8], qo[2][8];
#pragma unroll
  for (int rl = 0; rl < 2; ++rl)
#pragma unroll
    for (int fn = 0; fn < 8; ++fn) { so[rl][fn] = 0.f; qo[rl][fn] = 0.f; }
#pragma unroll
  for (int pc = 0; pc < 8; ++pc) {
    const int rl = pc >> 2, pq = pc & 3;
    const size_t rowoff = (size_t)(n * HH + h0 + 2 * wm + rl) * HH * CCH;
#pragma unroll
    for (int r = 0; r < 4; ++r) {
      int w = pq * 16 + g * 4 + r;
      if (w < HH) {
#pragma unroll
        for (int fn = 0; fn < 8; ++fn) {
          float v = acc[pc][fn][r];
          so[rl][fn] += v;
          qo[rl][fn] += v * v;
          outb[rowoff + (size_t)w * CCH + wn * 128 + fn * 16 + li] = (bf16)v;
        }
      }
    }
  }
#pragma unroll
  for (int rl = 0; rl < 2; ++rl)
#pragma unroll
    for (int fn = 0; fn < 8; ++fn) {
      so[rl][fn] += __shfl_xor(so[rl][fn], 16);
      so[rl][fn] += __shfl_xor(so[rl][fn], 32);
      qo[rl][fn] += __shfl_xor(qo[rl][fn], 16);
      qo[rl][fn] += __shfl_xor(qo[rl][fn], 32);
    }
  if (g == 0) {
#pragma unroll
    for (int rl = 0; rl < 2; ++rl)
#pragma unroll
      for (int fn = 0; fn < 8; ++fn) {
        int o = wn * 128 + fn * 16 + lane;
        size_t prow = (size_t)(bid * 4 + 2 * wm + rl);
        part[(prow * CCH + o) * 2 + 0] = so[rl][fn];
        part[(prow * CCH + o) * 2 + 1] = qo[rl][fn];
      }
  }
}

// ---------------- fuse2: bn2 + residual + relu + NHWC->NCHW (vectorized) ----------------
__global__ __launch_bounds__(256) void fuse2(const bf16* __restrict__ raw,
                                             const bf16* __restrict__ v1pad,
                                             const float* __restrict__ bnp,
                                             float* __restrict__ out) {
  __shared__ float tile[CCH * 57];   // [c][w], odd stride
  int bid = blockIdx.x;
  int n = bid / HH, h = bid % HH;
  int t = threadIdx.x;
  const bf16* rrow = raw + (size_t)(n * HH + h) * HH * CCH;
  const bf16* vrow = v1pad + ((size_t)(n * HP + h + 1) * HP + 1) * CCH;
  const int cg = t & 31;
  float sc[8], bi[8];
#pragma unroll
  for (int q = 0; q < 8; ++q) {
    sc[q] = bnp[(cg * 8 + q) * 2];
    bi[q] = bnp[(cg * 8 + q) * 2 + 1];
  }
  for (int j = t; j < HH * 32; j += 256) {
    int w = j >> 5;                    // (j & 31) == cg
    bf16x8 r8 = *(const bf16x8*)(rrow + (size_t)w * CCH + cg * 8);
    bf16x8 v8 = *(const bf16x8*)(vrow + (size_t)w * CCH + cg * 8);
#pragma unroll
    for (int q = 0; q < 8; ++q) {
      float v = (float)r8[q] * sc[q] + bi[q] + (float)v8[q];
      tile[(cg * 8 + q) * 57 + w] = v > 0.f ? v : 0.f;
    }
  }
  __syncthreads();
  float* ob = out + (size_t)n * CCH * (HH * HH) + (size_t)h * HH;
  for (int j = t; j < CCH * 14; j += 256) {
    int c = j / 14, wq = j % 14;
    const float* tp = &tile[c * 57 + wq * 4];
    float4 v = {tp[0], tp[1], tp[2], tp[3]};
    *(float4*)(ob + (size_t)c * (HH * HH) + wq * 4) = v;
  }
}

// ---------------- BN reduce: 896 partial rows -> affine params (2-stage) ----------------
__global__ __launch_bounds__(256) void bn_reduce1(const float* __restrict__ part,
                                                  float* __restrict__ part2) {
  int t = threadIdx.x, b = blockIdx.x;   // 32 blocks, 28 rows each
  float s = 0.f, q = 0.f;
  for (int r = b * 28; r < (b + 1) * 28; r++) {
    s += part[((size_t)r * CCH + t) * 2 + 0];
    q += part[((size_t)r * CCH + t) * 2 + 1];
  }
  part2[((size_t)b * CCH + t) * 2 + 0] = s;
  part2[((size_t)b * CCH + t) * 2 + 1] = q;
}

__global__ __launch_bounds__(256) void bn_reduce2(const float* __restrict__ part2,
                                                  const float* __restrict__ gamma,
                                                  const float* __restrict__ beta,
                                                  float* __restrict__ params) {
  int t = threadIdx.x;   // channel
  float s = 0.f, q = 0.f;
  for (int b = 0; b < 32; b++) {
    s += part2[((size_t)b * CCH + t) * 2 + 0];
    q += part2[((size_t)b * CCH + t) * 2 + 1];
  }
  const float inv = 1.f / (float)NPOSV;
  float mean = s * inv;
  float var = q * inv - mean * mean;
  float sc = gamma[t] / sqrtf(var + 1e-5f);
  params[t * 2 + 0] = sc;
  params[t * 2 + 1] = beta[t] - mean * sc;
}

// ---------------- BN apply + relu + pad: bf16 raw -> bf16 NHWC padded (vectorized) ----------------
__global__ __launch_bounds__(256) void bn_apply_b(const bf16* __restrict__ rawb,
                                                  const float* __restrict__ params,
                                                  bf16* __restrict__ xpad) {
  int bid = blockIdx.x;
  int hp = bid % HP;
  int n = bid / HP;
  int t = threadIdx.x;
  bf16* orow = xpad + (size_t)(n * HP + hp) * HP * CCH;
  bf16x8 z;
#pragma unroll
  for (int q = 0; q < 8; ++q) z[q] = (bf16)0.f;
  if (hp == 0 || hp == HP - 1) {
    for (int j = t; j < HP * 32; j += 256)
      *(bf16x8*)(orow + (size_t)(j >> 5) * CCH + (j & 31) * 8) = z;
    return;
  }
  const int cg = t & 31, ws8 = t >> 5;
  float sc[8], bi[8];
#pragma unroll
  for (int q = 0; q < 8; ++q) {
    sc[q] = params[(cg * 8 + q) * 2];
    bi[q] = params[(cg * 8 + q) * 2 + 1];
  }
  const bf16* rrow = rawb + (size_t)(n * HH + (hp - 1)) * HH * CCH;
  for (int wp = ws8; wp < HP; wp += 8) {
    bf16x8 ov = z;
    if (wp >= 1 && wp <= HH) {
      bf16x8 r8 = *(const bf16x8*)(rrow + (size_t)(wp - 1) * CCH + cg * 8);
#pragma unroll
      for (int q = 0; q < 8; ++q) {
        float v = (float)r8[q] * sc[q] + bi[q];
        ov[q] = (bf16)(v > 0.f ? v : 0.f);
      }
    }
    *(bf16x8*)(orow + (size_t)wp * CCH + cg * 8) = ov;
  }
}

// ---------------- launch ----------------

extern "C" void kernel_launch(void* const* d_in, const int* in_sizes, int n_in,
                              void* d_out, int out_size, void* d_ws, size_t ws_size,
                              hipStream_t stream) {
  const float* x  = (const float*)d_in[0];
  const float* w1 = (const float*)d_in[1];
  const float* w2 = (const float*)d_in[2];
  const float* g1 = (const float*)d_in[3];
  const float* b1 = (const float*)d_in[4];
  const float* g2 = (const float*)d_in[5];
  const float* b2 = (const float*)d_in[6];
  float* out = (float*)d_out;
  char* ws = (char*)d_ws;

  constexpr size_t O_BT1  = 0;                                   // 1,179,648
  constexpr size_t O_BT2  = O_BT1 + 1179648;
  constexpr size_t O_XPAD = O_BT2 + 1179648;                     // 27,557,888 (+64K tail pad)
  constexpr size_t O_PART = O_XPAD + (size_t)NIMG * HP * HP * CCH * 2 + 65536;
  constexpr size_t O_PSUM = O_PART + (size_t)NPART * CCH * 2 * 4; // part: 1,835,008
  constexpr size_t O_PMN  = O_PSUM + 2048;
  constexpr size_t O_PMX  = O_PMN + 1024;
  constexpr size_t O_WQ   = O_PMX + 1024;
  constexpr size_t O_BNP1 = O_WQ + 256;
  constexpr size_t O_BNP2 = O_BNP1 + 2048;
  constexpr size_t O_PART2 = O_BNP2 + 2048;                      // 65,536
  constexpr size_t O_OUT2RAW = O_PART2 + 65536;                  // 25,690,112

  bf16* bt1 = (bf16*)(ws + O_BT1);
  bf16* bt2 = (bf16*)(ws + O_BT2);
  bf16* xpad = (bf16*)(ws + O_XPAD);
  bf16* out1pad = (bf16*)(ws + O_XPAD);   // reuses xpad space after conv1
  float* part = (float*)(ws + O_PART);
  double* psum = (double*)(ws + O_PSUM);
  float* pmn = (float*)(ws + O_PMN);
  float* pmx = (float*)(ws + O_PMX);
  float* wq = (float*)(ws + O_WQ);
  float* bnp1 = (float*)(ws + O_BNP1);
  float* bnp2 = (float*)(ws + O_BNP2);
  float* part2 = (float*)(ws + O_PART2);
  bf16* out2raw = (bf16*)(ws + O_OUT2RAW);
  bf16* out1rawb = (bf16*)d_out;   // d_out holds conv1 bf16 raw; dead before fuse2 writes

  w_partial<<<256, 256, 0, stream>>>(w1, w2, psum, pmn, pmx);
  w_finalize<<<1, 64, 0, stream>>>(psum, pmn, pmx, wq);
  w_quant<<<4608, 256, 0, stream>>>(w1, w2, wq, bt1, bt2);
  pad_convert<<<NIMG * HP, 256, 0, stream>>>(x, xpad);
  conv_gemm<<<NBLK, 256, 0, stream>>>(xpad, bt1, part, out1rawb);
  bn_reduce1<<<32, 256, 0, stream>>>(part, part2);
  bn_reduce2<<<1, 256, 0, stream>>>(part2, g1, b1, bnp1);
  bn_apply_b<<<NIMG * HP, 256, 0, stream>>>(out1rawb, bnp1, out1pad);
  conv_gemm<<<NBLK, 256, 0, stream>>>(out1pad, bt2, part, out2raw);
  bn_reduce1<<<32, 256, 0, stream>>>(part, part2);
  bn_reduce2<<<1, 256, 0, stream>>>(part2, g2, b2, bnp2);
  fuse2<<<NIMG * HH, 256, 0, stream>>>(out2raw, out1pad, bnp2, out);
}

// Round 12
// 191.931 us; speedup vs baseline: 1.2556x; 1.1449x over previous
//
#include <hip/hip_runtime.h>

typedef __bf16 bf16;
typedef __bf16 bf16x8 __attribute__((ext_vector_type(8)));
typedef float f32x4 __attribute__((ext_vector_type(4)));

#define NIMG 16
#define CCH 256
#define HH 56
#define HP 58
#define NBLK (NIMG * 14)         // 224 conv blocks (4 rows each)
#define NPART 896                // 224 blocks * 4 rows
#define NPOSV (NIMG * HH * HH)   // 50176 valid positions
#define WELEMS 589824            // 256*256*3*3
#define NPADB (NIMG * HP)        // 928 pad blocks

typedef const __attribute__((address_space(1))) void* gas1_t;
typedef __attribute__((address_space(3))) void* las3_t;

__device__ __forceinline__ void gload16(const void* g, void* l) {
  __builtin_amdgcn_global_load_lds((gas1_t)g, (las3_t)l, 16, 0, 0);
}

// ---------------- K1: pad_convert (0..927) | w_partial (928..1183) | zero cnt (1184) ----
__global__ __launch_bounds__(256) void pre_kernel(const float* __restrict__ x,
                                                  bf16* __restrict__ xpad,
                                                  const float* __restrict__ w1,
                                                  const float* __restrict__ w2,
                                                  double* __restrict__ psum,
                                                  float* __restrict__ pmn,
                                                  float* __restrict__ pmx,
                                                  unsigned* __restrict__ cnt) {
  __shared__ __align__(16) char sm[58368];
  const int blk = blockIdx.x;
  const int t = threadIdx.x;

  if (blk >= NPADB + 256) {          // counter zeroing
    if (t < 8) cnt[t] = 0u;
    return;
  }

  if (blk >= NPADB) {                // ---- w_partial ----
    int b = blk - NPADB;             // 0..255
    int lb = b & 127;
    const float* w = (b >> 7) ? w2 : w1;
    double s = 0.0;
    float mn = 3.4028235e38f, mx = -3.4028235e38f;
    for (int i = lb * 4608 + t; i < (lb + 1) * 4608; i += 256) {
      float v = w[i];
      s += (double)v;
      mn = fminf(mn, v);
      mx = fmaxf(mx, v);
    }
    double* sd = (double*)sm;                   // 2048 B
    float* smn = (float*)(sm + 2048);           // 1024 B
    float* smx = (float*)(sm + 3072);           // 1024 B
    sd[t] = s; smn[t] = mn; smx[t] = mx;
    __syncthreads();
    for (int st = 128; st > 0; st >>= 1) {
      if (t < st) {
        sd[t] += sd[t + st];
        smn[t] = fminf(smn[t], smn[t + st]);
        smx[t] = fmaxf(smx[t], smx[t + st]);
      }
      __syncthreads();
    }
    if (t == 0) { psum[b] = sd[0]; pmn[b] = smn[0]; pmx[b] = smx[0]; }
    return;
  }

  // ---- pad_convert ----
  int hp = blk % HP;
  int n = blk / HP;
  bf16* orow = xpad + (size_t)(n * HP + hp) * HP * CCH;
  bf16x8 z;
#pragma unroll
  for (int q = 0; q < 8; ++q) z[q] = (bf16)0.f;
  if (hp == 0 || hp == HP - 1) {
    for (int j = t; j < HP * 32; j += 256)
      *(bf16x8*)(orow + (size_t)(j >> 5) * CCH + (j & 31) * 8) = z;
    return;
  }
  float* tile = (float*)sm;                     // CCH*57 floats = 58368 B
  const float* xb = x + (size_t)n * CCH * (HH * HH) + (size_t)(hp - 1) * HH;
  for (int j = t; j < CCH * 14; j += 256) {
    int c = j / 14, wq = j % 14;
    float4 v = *(const float4*)(xb + (size_t)c * (HH * HH) + wq * 4);
    float* tp = &tile[c * 57 + wq * 4];
    tp[0] = v.x; tp[1] = v.y; tp[2] = v.z; tp[3] = v.w;
  }
  __syncthreads();
  const int cg = t & 31;
  for (int j = t; j < HP * 32; j += 256) {
    int wp = j >> 5;                 // (j & 31) == cg
    bf16x8 ov = z;
    if (wp >= 1 && wp <= HH) {
#pragma unroll
      for (int q = 0; q < 8; ++q) ov[q] = (bf16)tile[(cg * 8 + q) * 57 + (wp - 1)];
    }
    *(bf16x8*)(orow + (size_t)wp * CCH + cg * 8) = ov;
  }
}

// ---------------- K2: w_quant with in-block finalize ----------------
// Fragment-major B table: element e = fragidx*512 + l*8 + ki
// fragidx = ((s*4+cc)*2+kk)*16 + ob ; lane l: o = ob*16+(l&15), c = cc*64+kk*32+(l>>4)*8+ki
__global__ __launch_bounds__(256) void w_quant(const float* __restrict__ w1,
                                               const float* __restrict__ w2,
                                               const double* __restrict__ psum,
                                               const float* __restrict__ pmn,
                                               const float* __restrict__ pmx,
                                               bf16* __restrict__ btf1,
                                               bf16* __restrict__ btf2) {
  int bid = blockIdx.x;          // 4608 blocks
  int widx = bid / 2304;
  const float* w = widx ? w2 : w1;
  bf16* bt = widx ? btf2 : btf1;
  int t = threadIdx.x;
  // in-block finalize (reads 128 psum/pmn/pmx entries, L2-hot)
  __shared__ double sd[128];
  __shared__ float smn[128], smx[128];
  __shared__ float s_mean, s_lo, s_hi;
  if (t < 128) {
    sd[t] = psum[widx * 128 + t];
    smn[t] = pmn[widx * 128 + t];
    smx[t] = pmx[widx * 128 + t];
  }
  __syncthreads();
  for (int st = 64; st > 0; st >>= 1) {
    if (t < st) {
      sd[t] += sd[t + st];
      smn[t] = fminf(smn[t], smn[t + st]);
      smx[t] = fmaxf(smx[t], smx[t + st]);
    }
    __syncthreads();
  }
  if (t == 0) {
    float mean = (float)(sd[0] / (double)WELEMS);
    float tmn = smn[0] - mean, tmx = smx[0] - mean;
    float d = (tmx - tmn) / 3.0f;
    s_mean = mean;
    s_lo = tmn + d;
    s_hi = tmx - d;
  }
  __syncthreads();
  float mean = s_mean, lo = s_lo, hi = s_hi;

  int e = (bid % 2304) * 256 + t;
  int ki = e & 7;
  int l = (e >> 3) & 63;
  int frag = e >> 9;
  int ob = frag & 15;
  int rest = frag >> 4;
  int kk = rest & 1;
  int scc = rest >> 1;
  int cc = scc & 3;
  int s = scc >> 2;
  int o = ob * 16 + (l & 15);
  int c = cc * 64 + kk * 32 + (l >> 4) * 8 + ki;
  float tv = w[(size_t)o * 2304 + c * 9 + s] - mean;
  float q = tv < lo ? -1.f : (tv > hi ? 1.f : 0.f);
  if (s == 4) q *= 2.f;          // fold the "extra" center einsum in
  bt[e] = (bf16)q;
}

// ---------------- conv as implicit GEMM (r9 structure, frozen) ----------------
// block 256Mx256N, 8 waves, wave tile 128x64; fused BN stats + raw bf16 NHWC write.
__global__ __launch_bounds__(512, 2) void conv_gemm(const bf16* __restrict__ xpad,
                                                    const bf16* __restrict__ btf,
                                                    float* __restrict__ part,
                                                    bf16* __restrict__ outb) {
  __shared__ __align__(16) char smem[98304];   // 2 x 48KB A double-buffer
  const int t = threadIdx.x;
  const int lane = t & 63, wv = t >> 6;
  const int wm = wv >> 2, wn = wv & 3;          // wave: rows 2wm..2wm+1, o-chunk wn
  const int g = lane >> 4, li = lane & 15;
  const int rawbid = blockIdx.x;
  const int bid = (rawbid & 7) * (NBLK / 8) + (rawbid >> 3);  // XCD-contiguous swizzle
  const int n = bid / 14, h0 = (bid % 14) * 4;

  f32x4 acc[8][4];
#pragma unroll
  for (int i = 0; i < 8; i++)
#pragma unroll
    for (int j = 0; j < 4; j++) acc[i][j] = f32x4{0.f, 0.f, 0.f, 0.f};

  auto stageA = [&](int cc, int b) {
#pragma unroll
    for (int i = 0; i < 6; ++i) {
      int idx = wv + i * 8;              // 0..47
      int rr = idx >> 3, po = idx & 7;
      int pp = po * 8 + (lane >> 3);
      int gs = (lane & 7) ^ (lane >> 3); // inverse swizzle on source (pp&7 == lane>>3)
      const bf16* src = xpad + ((size_t)(n * HP + h0 + rr) * HP + pp) * CCH + cc * 64 + gs * 8;
      gload16(src, smem + b * 49152 + rr * 8192 + po * 1024 + lane * 16);
    }
  };

  auto loadB = [&](bf16x8 (&dst)[4], int s, int cc, int kk) {
#pragma unroll
    for (int f = 0; f < 4; ++f) {
      size_t fragidx = (size_t)(((s * 4 + cc) * 2 + kk) * 16 + wn * 4 + f);
      dst[f] = *(const bf16x8*)(btf + fragidx * 512 + lane * 8);
    }
  };

  auto compute_half = [&](const char* Ab, int half, int dh, int dw, int kk,
                          const bf16x8 (&bx)[4]) {
    bf16x8 a[4];
    int rr = 2 * wm + half + dh;
#pragma unroll
    for (int pc = 0; pc < 4; ++pc) {
      int p = pc * 16 + li + dw;
      int sl = (kk * 4 + g) ^ (p & 7);
      a[pc] = *(const bf16x8*)(Ab + rr * 8192 + p * 128 + sl * 16);
    }
#pragma unroll
    for (int pc = 0; pc < 4; ++pc)
#pragma unroll
      for (int fn = 0; fn < 4; ++fn)
        acc[half * 4 + pc][fn] =
          __builtin_amdgcn_mfma_f32_16x16x32_bf16(a[pc], bx[fn], acc[half * 4 + pc][fn], 0, 0, 0);
  };

  stageA(0, 0);
  bf16x8 bS[2][4];   // kk=0 ping-pong, prefetched one full tap-phase ahead
  bf16x8 bB[4];      // kk=1, loaded at phase start, covered by kk=0 compute
  loadB(bS[0], 0, 0, 0);
  __syncthreads();

#pragma unroll
  for (int cc = 0; cc < 4; ++cc) {
    const char* Ab = smem + (cc & 1) * 49152;
    if (cc < 3) stageA(cc + 1, (cc + 1) & 1);
#pragma unroll
    for (int s = 0; s < 9; ++s) {
      const int dh = s / 3, dw = s % 3;
      const int cur = (cc * 9 + s) & 1, nxt = cur ^ 1;
      if (s < 8) loadB(bS[nxt], s + 1, cc, 0);
      else if (cc < 3) loadB(bS[nxt], 0, cc + 1, 0);
      loadB(bB, s, cc, 1);
      __builtin_amdgcn_sched_barrier(0);   // keep load issues above the MFMA cluster
      __builtin_amdgcn_s_setprio(1);
      compute_half(Ab, 0, dh, dw, 0, bS[cur]);
      compute_half(Ab, 1, dh, dw, 0, bS[cur]);
      compute_half(Ab, 0, dh, dw, 1, bB);
      compute_half(Ab, 1, dh, dw, 1, bB);
      __builtin_amdgcn_s_setprio(0);
    }
    __syncthreads();
  }

  float so[2][4] = {{0.f,0.f,0.f,0.f},{0.f,0.f,0.f,0.f}};
  float qo[2][4] = {{0.f,0.f,0.f,0.f},{0.f,0.f,0.f,0.f}};
#pragma unroll
  for (int fm = 0; fm < 8; ++fm) {
    const int rl = fm >> 2, pc = fm & 3;
    const size_t rowoff = (size_t)(n * HH + h0 + 2 * wm + rl) * HH * CCH;
#pragma unroll
    for (int r = 0; r < 4; ++r) {
      int w = pc * 16 + g * 4 + r;
      if (w < HH) {
#pragma unroll
        for (int fn = 0; fn < 4; ++fn) {
          float v = acc[fm][fn][r];
          so[rl][fn] += v;
          qo[rl][fn] += v * v;
          outb[rowoff + (size_t)w * CCH + wn * 64 + fn * 16 + li] = (bf16)v;
        }
      }
    }
  }
#pragma unroll
  for (int rl = 0; rl < 2; ++rl)
#pragma unroll
    for (int fn = 0; fn < 4; ++fn) {
      so[rl][fn] += __shfl_xor(so[rl][fn], 16);
      so[rl][fn] += __shfl_xor(so[rl][fn], 32);
      qo[rl][fn] += __shfl_xor(qo[rl][fn], 16);
      qo[rl][fn] += __shfl_xor(qo[rl][fn], 32);
    }
  if (g == 0) {
#pragma unroll
    for (int rl = 0; rl < 2; ++rl)
#pragma unroll
      for (int fn = 0; fn < 4; ++fn) {
        int o = wn * 64 + fn * 16 + lane;
        size_t prow = (size_t)(bid * 4 + 2 * wm + rl);
        part[(prow * CCH + o) * 2 + 0] = so[rl][fn];
        part[(prow * CCH + o) * 2 + 1] = qo[rl][fn];
      }
  }
}

// ---------------- BN reduce: single kernel, last-block finalize ----------------
__global__ __launch_bounds__(256) void bn_reduce(const float* __restrict__ part,
                                                 float* __restrict__ part2,
                                                 const float* __restrict__ gamma,
                                                 const float* __restrict__ beta,
                                                 float* __restrict__ params,
                                                 unsigned* __restrict__ cnt) {
  int t = threadIdx.x, b = blockIdx.x;   // 32 blocks, 28 rows each
  float s = 0.f, q = 0.f;
  for (int r = b * 28; r < (b + 1) * 28; r++) {
    s += part[((size_t)r * CCH + t) * 2 + 0];
    q += part[((size_t)r * CCH + t) * 2 + 1];
  }
  part2[((size_t)b * CCH + t) * 2 + 0] = s;
  part2[((size_t)b * CCH + t) * 2 + 1] = q;
  __threadfence();
  __syncthreads();
  __shared__ unsigned ticket;
  if (t == 0) ticket = atomicAdd(cnt, 1u);
  __syncthreads();
  if (ticket == 31u) {                   // last block finalizes (deterministic order)
    __threadfence();
    float s2 = 0.f, q2 = 0.f;
    for (int b2 = 0; b2 < 32; b2++) {
      s2 += part2[((size_t)b2 * CCH + t) * 2 + 0];
      q2 += part2[((size_t)b2 * CCH + t) * 2 + 1];
    }
    const float inv = 1.f / (float)NPOSV;
    float mean = s2 * inv;
    float var = q2 * inv - mean * mean;
    float sc = gamma[t] / sqrtf(var + 1e-5f);
    params[t * 2 + 0] = sc;
    params[t * 2 + 1] = beta[t] - mean * sc;
  }
}

// ---------------- BN apply + relu + pad: bf16 raw -> bf16 NHWC padded ----------------
__global__ __launch_bounds__(256) void bn_apply_b(const bf16* __restrict__ rawb,
                                                  const float* __restrict__ params,
                                                  bf16* __restrict__ xpad) {
  int bid = blockIdx.x;
  int hp = bid % HP;
  int n = bid / HP;
  int t = threadIdx.x;
  bf16* orow = xpad + (size_t)(n * HP + hp) * HP * CCH;
  bf16x8 z;
#pragma unroll
  for (int q = 0; q < 8; ++q) z[q] = (bf16)0.f;
  if (hp == 0 || hp == HP - 1) {
    for (int j = t; j < HP * 32; j += 256)
      *(bf16x8*)(orow + (size_t)(j >> 5) * CCH + (j & 31) * 8) = z;
    return;
  }
  const int cg = t & 31, ws8 = t >> 5;
  float sc[8], bi[8];
#pragma unroll
  for (int q = 0; q < 8; ++q) {
    sc[q] = params[(cg * 8 + q) * 2];
    bi[q] = params[(cg * 8 + q) * 2 + 1];
  }
  const bf16* rrow = rawb + (size_t)(n * HH + (hp - 1)) * HH * CCH;
  for (int wp = ws8; wp < HP; wp += 8) {
    bf16x8 ov = z;
    if (wp >= 1 && wp <= HH) {
      bf16x8 r8 = *(const bf16x8*)(rrow + (size_t)(wp - 1) * CCH + cg * 8);
#pragma unroll
      for (int q = 0; q < 8; ++q) {
        float v = (float)r8[q] * sc[q] + bi[q];
        ov[q] = (bf16)(v > 0.f ? v : 0.f);
      }
    }
    *(bf16x8*)(orow + (size_t)wp * CCH + cg * 8) = ov;
  }
}

// ---------------- fuse2: bn2 + residual + relu + NHWC->NCHW (vectorized) ----------------
__global__ __launch_bounds__(256) void fuse2(const bf16* __restrict__ raw,
                                             const bf16* __restrict__ v1pad,
                                             const float* __restrict__ bnp,
                                             float* __restrict__ out) {
  __shared__ float tile[CCH * 57];   // [c][w], odd stride
  int bid = blockIdx.x;
  int n = bid / HH, h = bid % HH;
  int t = threadIdx.x;
  const bf16* rrow = raw + (size_t)(n * HH + h) * HH * CCH;
  const bf16* vrow = v1pad + ((size_t)(n * HP + h + 1) * HP + 1) * CCH;
  const int cg = t & 31;
  float sc[8], bi[8];
#pragma unroll
  for (int q = 0; q < 8; ++q) {
    sc[q] = bnp[(cg * 8 + q) * 2];
    bi[q] = bnp[(cg * 8 + q) * 2 + 1];
  }
  for (int j = t; j < HH * 32; j += 256) {
    int w = j >> 5;                    // (j & 31) == cg
    bf16x8 r8 = *(const bf16x8*)(rrow + (size_t)w * CCH + cg * 8);
    bf16x8 v8 = *(const bf16x8*)(vrow + (size_t)w * CCH + cg * 8);
#pragma unroll
    for (int q = 0; q < 8; ++q) {
      float v = (float)r8[q] * sc[q] + bi[q] + (float)v8[q];
      tile[(cg * 8 + q) * 57 + w] = v > 0.f ? v : 0.f;
    }
  }
  __syncthreads();
  float* ob = out + (size_t)n * CCH * (HH * HH) + (size_t)h * HH;
  for (int j = t; j < CCH * 14; j += 256) {
    int c = j / 14, wq = j % 14;
    const float* tp = &tile[c * 57 + wq * 4];
    float4 v = {tp[0], tp[1], tp[2], tp[3]};
    *(float4*)(ob + (size_t)c * (HH * HH) + wq * 4) = v;
  }
}

// ---------------- launch ----------------

extern "C" void kernel_launch(void* const* d_in, const int* in_sizes, int n_in,
                              void* d_out, int out_size, void* d_ws, size_t ws_size,
                              hipStream_t stream) {
  const float* x  = (const float*)d_in[0];
  const float* w1 = (const float*)d_in[1];
  const float* w2 = (const float*)d_in[2];
  const float* g1 = (const float*)d_in[3];
  const float* b1 = (const float*)d_in[4];
  const float* g2 = (const float*)d_in[5];
  const float* b2 = (const float*)d_in[6];
  float* out = (float*)d_out;
  char* ws = (char*)d_ws;

  constexpr size_t O_BT1  = 0;                                   // 1,179,648
  constexpr size_t O_BT2  = O_BT1 + 1179648;
  constexpr size_t O_XPAD = O_BT2 + 1179648;                     // 27,557,888 (+64K tail pad)
  constexpr size_t O_PART = O_XPAD + (size_t)NIMG * HP * HP * CCH * 2 + 65536;
  constexpr size_t O_PSUM = O_PART + (size_t)NPART * CCH * 2 * 4; // part: 1,835,008
  constexpr size_t O_PMN  = O_PSUM + 2048;
  constexpr size_t O_PMX  = O_PMN + 1024;
  constexpr size_t O_BNP1 = O_PMX + 1024;
  constexpr size_t O_BNP2 = O_BNP1 + 2048;
  constexpr size_t O_PART2 = O_BNP2 + 2048;                      // 65,536
  constexpr size_t O_CNT  = O_PART2 + 65536;                     // 32 B
  constexpr size_t O_OUT2RAW = O_CNT + 65536;                    // 25,690,112

  bf16* bt1 = (bf16*)(ws + O_BT1);
  bf16* bt2 = (bf16*)(ws + O_BT2);
  bf16* xpad = (bf16*)(ws + O_XPAD);
  bf16* out1pad = (bf16*)(ws + O_XPAD);   // reuses xpad space after conv1
  float* part = (float*)(ws + O_PART);
  double* psum = (double*)(ws + O_PSUM);
  float* pmn = (float*)(ws + O_PMN);
  float* pmx = (float*)(ws + O_PMX);
  float* bnp1 = (float*)(ws + O_BNP1);
  float* bnp2 = (float*)(ws + O_BNP2);
  float* part2 = (float*)(ws + O_PART2);
  unsigned* cnt = (unsigned*)(ws + O_CNT);
  bf16* out2raw = (bf16*)(ws + O_OUT2RAW);
  bf16* out1rawb = (bf16*)d_out;   // d_out holds conv1 bf16 raw; dead before fuse2 writes

  pre_kernel<<<NPADB + 256 + 1, 256, 0, stream>>>(x, xpad, w1, w2, psum, pmn, pmx, cnt);
  w_quant<<<4608, 256, 0, stream>>>(w1, w2, psum, pmn, pmx, bt1, bt2);
  conv_gemm<<<NBLK, 512, 0, stream>>>(xpad, bt1, part, out1rawb);
  bn_reduce<<<32, 256, 0, stream>>>(part, part2, g1, b1, bnp1, cnt + 0);
  bn_apply_b<<<NIMG * HP, 256, 0, stream>>>(out1rawb, bnp1, out1pad);
  conv_gemm<<<NBLK, 512, 0, stream>>>(out1pad, bt2, part, out2raw);
  bn_reduce<<<32, 256, 0, stream>>>(part, part2, g2, b2, bnp2, cnt + 1);
  fuse2<<<NIMG * HH, 256, 0, stream>>>(out2raw, out1pad, bnp2, out);
}